// Round 1
// baseline (346.279 us; speedup 1.0000x reference)
//
#include <hip/hip_runtime.h>

#define K_DIM 2048
#define N_DIM 2048
#define M_DIM 16384

typedef int v4i __attribute__((ext_vector_type(4)));
typedef int v16i __attribute__((ext_vector_type(16)));

// ---------------- ws layout ----------------
// [0]       double part[256]      (2 KB)
// [2048]    float  invsw          (= clip(mean|W|,1e-5))
// [4096]    float  si[16384]      (64 KB)
// [69632]   int8   qw_t           (4 MiB)  tiled [bn(16)][ks(32)][k16(4)][row(128)][16B]
// [4263936] int8   qx_t           (32 MiB) tiled [bm(64)][ks(32)][k16(4)][row(256)][16B]

__device__ __forceinline__ void lds16(const void* g, void* l) {
    __builtin_amdgcn_global_load_lds(
        (const __attribute__((address_space(1))) unsigned int*)g,
        (__attribute__((address_space(3))) unsigned int*)l,
        16, 0, 0);
}

// ---------- kernel 1: per-block |W| partial sums ----------
__global__ __launch_bounds__(256) void k_wsum(const float* __restrict__ w,
                                              double* __restrict__ part) {
    int tid = blockIdx.x * 256 + threadIdx.x;
    const float4* w4 = (const float4*)w;
    double s = 0.0;
    for (int i = tid; i < (N_DIM * K_DIM / 4); i += 65536) {
        float4 v = w4[i];
        s += (double)fabsf(v.x);
        s += (double)fabsf(v.y);
        s += (double)fabsf(v.z);
        s += (double)fabsf(v.w);
    }
#pragma unroll
    for (int off = 32; off; off >>= 1) s += __shfl_xor(s, off, 64);
    __shared__ double sp[4];
    int lane = threadIdx.x & 63, wv = threadIdx.x >> 6;
    if (lane == 0) sp[wv] = s;
    __syncthreads();
    if (threadIdx.x == 0) part[blockIdx.x] = sp[0] + sp[1] + sp[2] + sp[3];
}

// ---------- kernel 2: reduce partials inline + ternary-quantize W (swizzled out) ----------
__global__ __launch_bounds__(256) void k_quant_w(const float* __restrict__ w,
                                                 signed char* __restrict__ qw_t,
                                                 const double* __restrict__ part,
                                                 float* __restrict__ invsw_out) {
    double s = part[threadIdx.x];
#pragma unroll
    for (int off = 32; off; off >>= 1) s += __shfl_xor(s, off, 64);
    __shared__ double sp[4];
    __shared__ float s_invsw;
    int lane = threadIdx.x & 63, wv = threadIdx.x >> 6;
    if (lane == 0) sp[wv] = s;
    __syncthreads();
    if (threadIdx.x == 0) {
        double total = sp[0] + sp[1] + sp[2] + sp[3];
        float mean = (float)(total * (1.0 / (double)(N_DIM * K_DIM)));
        s_invsw = fmaxf(mean, 1e-5f);
        if (blockIdx.x == 0) *invsw_out = s_invsw;
    }
    __syncthreads();
    float sw = 1.0f / s_invsw;  // reference's sw

    int row = blockIdx.x * 4 + wv;           // 0..2047
    const float4* wr_ = (const float4*)(w + (size_t)row * K_DIM);
    int bn = row >> 7, ri = row & 127;
    signed char* base = qw_t + (size_t)bn * 262144 + (((lane >> 2) & 3) << 11) + (ri << 4) + ((lane & 3) << 2);
    int ksBase = lane >> 4;
#pragma unroll
    for (int c = 0; c < 8; c++) {
        float4 v = wr_[c * 64 + lane];
        int q0 = (int)fminf(fmaxf(rintf(v.x * sw), -1.f), 1.f);
        int q1 = (int)fminf(fmaxf(rintf(v.y * sw), -1.f), 1.f);
        int q2 = (int)fminf(fmaxf(rintf(v.z * sw), -1.f), 1.f);
        int q3 = (int)fminf(fmaxf(rintf(v.w * sw), -1.f), 1.f);
        int q = (q0 & 255) | ((q1 & 255) << 8) | ((q2 & 255) << 16) | ((q3 & 255) << 24);
        *(int*)(base + (size_t)(4 * c + ksBase) * 8192) = q;
    }
}

// ---------- kernel 3: per-row int8-quantize X (swizzled out) ----------
__global__ __launch_bounds__(256) void k_quant_x(const float* __restrict__ x,
                                                 signed char* __restrict__ qx_t,
                                                 float* __restrict__ si_out) {
    int row = blockIdx.x * 4 + (threadIdx.x >> 6);
    int lane = threadIdx.x & 63;
    const float4* xr = (const float4*)(x + (size_t)row * K_DIM);
    float4 v[8];
    float mx = 0.f;
#pragma unroll
    for (int c = 0; c < 8; c++) {
        v[c] = xr[c * 64 + lane];
        mx = fmaxf(mx, fmaxf(fmaxf(fabsf(v[c].x), fabsf(v[c].y)),
                             fmaxf(fabsf(v[c].z), fabsf(v[c].w))));
    }
#pragma unroll
    for (int off = 32; off; off >>= 1) mx = fmaxf(mx, __shfl_xor(mx, off, 64));
    float si = 127.0f / fmaxf(mx, 1e-5f);  // bit-exact vs reference
    if (lane == 0) si_out[row] = si;

    int bm = row >> 8, ri = row & 255;
    signed char* base = qx_t + (size_t)bm * 524288 + (((lane >> 2) & 3) << 12) + (ri << 4) + ((lane & 3) << 2);
    int ksBase = lane >> 4;
#pragma unroll
    for (int c = 0; c < 8; c++) {
        int q0 = (int)fminf(fmaxf(rintf(v[c].x * si), -128.f), 127.f);
        int q1 = (int)fminf(fmaxf(rintf(v[c].y * si), -128.f), 127.f);
        int q2 = (int)fminf(fmaxf(rintf(v[c].z * si), -128.f), 127.f);
        int q3 = (int)fminf(fmaxf(rintf(v[c].w * si), -128.f), 127.f);
        int q = (q0 & 255) | ((q1 & 255) << 8) | ((q2 & 255) << 16) | ((q3 & 255) << 24);
        *(int*)(base + (size_t)(4 * c + ksBase) * 16384) = q;
    }
}

// ---------- kernel 4: int8 GEMM, 256x128 block, 32x32x32 MFMA ----------
// ROUND 0 CHANGE: double-buffered LDS + prefetch (T3 "minimum 2-phase").
//   old: stage -> barrier(drain) -> compute -> barrier   (2 barriers, drain
//        of 48 KB/CU L2 staging serialized BEFORE compute each K-step)
//   new: prefetch next tile -> compute current -> ONE barrier (the
//        compiler-mandated vmcnt(0) drain lands AFTER ~1300 cyc of MFMA,
//        hiding L2 latency+transfer under compute)
// LDS: 48 KB/block -> 96 KB/CU at 2 blocks/CU (fits 160 KB).
__global__ __launch_bounds__(256, 2) void k_gemm(const signed char* __restrict__ qx_t,
                                                 const signed char* __restrict__ qw_t,
                                                 const float* __restrict__ si,
                                                 const float* __restrict__ invsw_p,
                                                 float* __restrict__ out) {
    __shared__ __align__(16) signed char As[2][16384];  // [k16(4)][row(256)][16B]
    __shared__ __align__(16) signed char Bs[2][8192];   // [k16(4)][row(128)][16B]
    const int t = threadIdx.x;
    const int lane = t & 63, wv = t >> 6;
    const int wr = wv >> 1, wc = wv & 1;   // 2x2 wave grid; wave tile 128x64
    const int l31 = lane & 31, lh = lane >> 5;
    const int bn = blockIdx.x, bm = blockIdx.y;

    const signed char* aT = qx_t + (size_t)bm * 524288;
    const signed char* bT = qw_t + (size_t)bn * 262144;
    const int t16 = t << 4;

#define STAGE(buf, ksv)                                      \
    {                                                        \
        const signed char* aS = aT + ((size_t)(ksv) << 14);  \
        const signed char* bS = bT + ((size_t)(ksv) << 13);  \
        signed char* Ad = As[buf];                           \
        signed char* Bd = Bs[buf];                           \
        lds16(aS + t16,         Ad + t16);                   \
        lds16(aS + 4096 + t16,  Ad + 4096 + t16);            \
        lds16(aS + 8192 + t16,  Ad + 8192 + t16);            \
        lds16(aS + 12288 + t16, Ad + 12288 + t16);           \
        lds16(bS + t16,         Bd + t16);                   \
        lds16(bS + 4096 + t16,  Bd + 4096 + t16);            \
    }

    v16i acc[4][2] = {};

    STAGE(0, 0);
    __syncthreads();  // implicit vmcnt(0): buf0 ready

    for (int ks = 0; ks < 32; ks++) {
        const int cur = ks & 1;
        if (ks < 31) STAGE(cur ^ 1, ks + 1);  // issue next-tile loads, do NOT drain

        const signed char* Ac = As[cur];
        const signed char* Bc = Bs[cur];
#pragma unroll
        for (int ks2 = 0; ks2 < 2; ks2++) {
            v4i af[4], bf[2];
#pragma unroll
            for (int mt = 0; mt < 4; mt++)
                af[mt] = *(const v4i*)(Ac + (((ks2 * 2 + lh) * 256 + wr * 128 + mt * 32 + l31) << 4));
#pragma unroll
            for (int nt = 0; nt < 2; nt++)
                bf[nt] = *(const v4i*)(Bc + (((ks2 * 2 + lh) * 128 + wc * 64 + nt * 32 + l31) << 4));
#pragma unroll
            for (int mt = 0; mt < 4; mt++)
#pragma unroll
                for (int nt = 0; nt < 2; nt++)
                    acc[mt][nt] = __builtin_amdgcn_mfma_i32_32x32x32_i8(af[mt], bf[nt], acc[mt][nt], 0, 0, 0);
        }
        // single barrier per K-step: compiler emits s_waitcnt vmcnt(0) lgkmcnt(0)
        // here, which (a) finishes the prefetch into buf^1 and (b) guarantees all
        // waves' ds_reads of buf are done before it is overwritten next iter.
        __syncthreads();
    }
#undef STAGE

    // epilogue: C/D 32x32 layout col=lane&31, row=(r&3)+8*(r>>2)+4*(lane>>5)
    float invsw = *invsw_p;
#pragma unroll
    for (int mt = 0; mt < 4; mt++) {
        int rowb = bm * 256 + wr * 128 + mt * 32 + (lh << 2);
        float sc[16];
#pragma unroll
        for (int r = 0; r < 16; r++)
            sc[r] = invsw / si[rowb + (r & 3) + ((r >> 2) << 3)];
#pragma unroll
        for (int nt = 0; nt < 2; nt++) {
            int col = bn * 128 + wc * 64 + nt * 32 + l31;
#pragma unroll
            for (int r = 0; r < 16; r++) {
                int row = rowb + (r & 3) + ((r >> 2) << 3);
                float vv = (float)acc[mt][nt][r] * sc[r];
                out[(size_t)row * N_DIM + col] = (float)(_Float16)vv;
            }
        }
    }
}

extern "C" void kernel_launch(void* const* d_in, const int* in_sizes, int n_in,
                              void* d_out, int out_size, void* d_ws, size_t ws_size,
                              hipStream_t stream) {
    const float* x = (const float*)d_in[0];
    const float* w = (const float*)d_in[1];
    float* out = (float*)d_out;
    char* ws = (char*)d_ws;

    double* part = (double*)ws;
    float* invsw = (float*)(ws + 2048);
    float* si = (float*)(ws + 4096);
    signed char* qw_t = (signed char*)(ws + 4096 + 65536);
    signed char* qx_t = qw_t + (size_t)N_DIM * K_DIM;

    k_wsum<<<256, 256, 0, stream>>>(w, part);
    k_quant_x<<<4096, 256, 0, stream>>>(x, qx_t, si);
    k_quant_w<<<512, 256, 0, stream>>>(w, qw_t, part, invsw);
    k_gemm<<<dim3(N_DIM / 128, M_DIM / 256), 256, 0, stream>>>(qx_t, qw_t, si, invsw, out);
}

// Round 2
// 323.172 us; speedup vs baseline: 1.0715x; 1.0715x over previous
//
#include <hip/hip_runtime.h>

#define K_DIM 2048
#define N_DIM 2048
#define M_DIM 16384

typedef int v4i __attribute__((ext_vector_type(4)));
typedef int v16i __attribute__((ext_vector_type(16)));

// ---------------- ws layout ----------------
// [0]       double part[256]      (2 KB)
// [2048]    float  invsw          (= clip(mean|W|,1e-5))
// [4096]    float  si[16384]      (64 KB)
// [69632]   int8   qw_t           (4 MiB)  tiled [bn(16)][ks(32)][k16(4)][row(128)][16B]
// [4263936] int8   qx_t           (32 MiB) tiled [bm(64)][ks(32)][k16(4)][row(256)][16B]

__device__ __forceinline__ void lds16(const void* g, void* l) {
    __builtin_amdgcn_global_load_lds(
        (const __attribute__((address_space(1))) unsigned int*)g,
        (__attribute__((address_space(3))) unsigned int*)l,
        16, 0, 0);
}

// ---------- kernel 1: per-block |W| partial sums ----------
__global__ __launch_bounds__(256) void k_wsum(const float* __restrict__ w,
                                              double* __restrict__ part) {
    int tid = blockIdx.x * 256 + threadIdx.x;
    const float4* w4 = (const float4*)w;
    double s = 0.0;
    for (int i = tid; i < (N_DIM * K_DIM / 4); i += 65536) {
        float4 v = w4[i];
        s += (double)fabsf(v.x);
        s += (double)fabsf(v.y);
        s += (double)fabsf(v.z);
        s += (double)fabsf(v.w);
    }
#pragma unroll
    for (int off = 32; off; off >>= 1) s += __shfl_xor(s, off, 64);
    __shared__ double sp[4];
    int lane = threadIdx.x & 63, wv = threadIdx.x >> 6;
    if (lane == 0) sp[wv] = s;
    __syncthreads();
    if (threadIdx.x == 0) part[blockIdx.x] = sp[0] + sp[1] + sp[2] + sp[3];
}

// ---------- kernel 2: reduce partials inline + ternary-quantize W (swizzled out) ----------
__global__ __launch_bounds__(256) void k_quant_w(const float* __restrict__ w,
                                                 signed char* __restrict__ qw_t,
                                                 const double* __restrict__ part,
                                                 float* __restrict__ invsw_out) {
    double s = part[threadIdx.x];
#pragma unroll
    for (int off = 32; off; off >>= 1) s += __shfl_xor(s, off, 64);
    __shared__ double sp[4];
    __shared__ float s_invsw;
    int lane = threadIdx.x & 63, wv = threadIdx.x >> 6;
    if (lane == 0) sp[wv] = s;
    __syncthreads();
    if (threadIdx.x == 0) {
        double total = sp[0] + sp[1] + sp[2] + sp[3];
        float mean = (float)(total * (1.0 / (double)(N_DIM * K_DIM)));
        s_invsw = fmaxf(mean, 1e-5f);
        if (blockIdx.x == 0) *invsw_out = s_invsw;
    }
    __syncthreads();
    float sw = 1.0f / s_invsw;  // reference's sw

    int row = blockIdx.x * 4 + wv;           // 0..2047
    const float4* wr_ = (const float4*)(w + (size_t)row * K_DIM);
    int bn = row >> 7, ri = row & 127;
    signed char* base = qw_t + (size_t)bn * 262144 + (((lane >> 2) & 3) << 11) + (ri << 4) + ((lane & 3) << 2);
    int ksBase = lane >> 4;
#pragma unroll
    for (int c = 0; c < 8; c++) {
        float4 v = wr_[c * 64 + lane];
        int q0 = (int)fminf(fmaxf(rintf(v.x * sw), -1.f), 1.f);
        int q1 = (int)fminf(fmaxf(rintf(v.y * sw), -1.f), 1.f);
        int q2 = (int)fminf(fmaxf(rintf(v.z * sw), -1.f), 1.f);
        int q3 = (int)fminf(fmaxf(rintf(v.w * sw), -1.f), 1.f);
        int q = (q0 & 255) | ((q1 & 255) << 8) | ((q2 & 255) << 16) | ((q3 & 255) << 24);
        *(int*)(base + (size_t)(4 * c + ksBase) * 8192) = q;
    }
}

// ---------- kernel 3: per-row int8-quantize X (swizzled out) ----------
__global__ __launch_bounds__(256) void k_quant_x(const float* __restrict__ x,
                                                 signed char* __restrict__ qx_t,
                                                 float* __restrict__ si_out) {
    int row = blockIdx.x * 4 + (threadIdx.x >> 6);
    int lane = threadIdx.x & 63;
    const float4* xr = (const float4*)(x + (size_t)row * K_DIM);
    float4 v[8];
    float mx = 0.f;
#pragma unroll
    for (int c = 0; c < 8; c++) {
        v[c] = xr[c * 64 + lane];
        mx = fmaxf(mx, fmaxf(fmaxf(fabsf(v[c].x), fabsf(v[c].y)),
                             fmaxf(fabsf(v[c].z), fabsf(v[c].w))));
    }
#pragma unroll
    for (int off = 32; off; off >>= 1) mx = fmaxf(mx, __shfl_xor(mx, off, 64));
    float si = 127.0f / fmaxf(mx, 1e-5f);  // bit-exact vs reference
    if (lane == 0) si_out[row] = si;

    int bm = row >> 8, ri = row & 255;
    signed char* base = qx_t + (size_t)bm * 524288 + (((lane >> 2) & 3) << 12) + (ri << 4) + ((lane & 3) << 2);
    int ksBase = lane >> 4;
#pragma unroll
    for (int c = 0; c < 8; c++) {
        int q0 = (int)fminf(fmaxf(rintf(v[c].x * si), -128.f), 127.f);
        int q1 = (int)fminf(fmaxf(rintf(v[c].y * si), -128.f), 127.f);
        int q2 = (int)fminf(fmaxf(rintf(v[c].z * si), -128.f), 127.f);
        int q3 = (int)fminf(fmaxf(rintf(v[c].w * si), -128.f), 127.f);
        int q = (q0 & 255) | ((q1 & 255) << 8) | ((q2 & 255) << 16) | ((q3 & 255) << 24);
        *(int*)(base + (size_t)(4 * c + ksBase) * 16384) = q;
    }
}

// ---------- kernel 4: int8 GEMM, 256x128 block, 32x32x32 MFMA ----------
// ROUND 1 CHANGE (T4 + T1):
//   * A triple-buffered (3x16KB), B double-buffered (2x8KB) = 64 KB static LDS.
//   * Counted s_waitcnt vmcnt(10) + raw s_barrier per K-step — NEVER drains to 0
//     in the main loop. Per-iter issue order [B(ks+1), A(ks+2)] makes vmcnt(10)
//     retire exactly {B(ks), A(ks)}: A-staging gets 2 compute phases of latency
//     budget, B (small, L2-hot) gets 1.
//   * XCD chunk swizzle: each XCD owns 8 contiguous bm slices -> concurrent
//     working set ~6 MB (fits L2) instead of ~20 MB.
__global__ __launch_bounds__(256, 2) void k_gemm(const signed char* __restrict__ qx_t,
                                                 const signed char* __restrict__ qw_t,
                                                 const float* __restrict__ si,
                                                 const float* __restrict__ invsw_p,
                                                 float* __restrict__ out) {
    __shared__ __align__(16) signed char As[3][16384];  // [k16(4)][row(256)][16B]
    __shared__ __align__(16) signed char Bs[2][8192];   // [k16(4)][row(128)][16B]
    const int t = threadIdx.x;
    const int lane = t & 63, wv = t >> 6;
    const int wr = wv >> 1, wc = wv & 1;   // 2x2 wave grid; wave tile 128x64
    const int l31 = lane & 31, lh = lane >> 5;

    // T1: bijective chunked XCD swizzle (nwg=1024, 8 XCDs, 128 blocks/XCD)
    const int wg = blockIdx.x;
    const int swz = (wg & 7) * 128 + (wg >> 3);
    const int bn = swz & 15, bm = swz >> 4;   // bn inner: XCD k owns bm in [8k, 8k+8)

    const signed char* aT = qx_t + (size_t)bm * 524288;
    const signed char* bT = qw_t + (size_t)bn * 262144;
    const int t16 = t << 4;

#define STAGE_A(buf, ksv)                                    \
    {                                                        \
        const signed char* aS = aT + ((size_t)(ksv) << 14);  \
        signed char* Ad = As[buf];                           \
        lds16(aS + t16,         Ad + t16);                   \
        lds16(aS + 4096 + t16,  Ad + 4096 + t16);            \
        lds16(aS + 8192 + t16,  Ad + 8192 + t16);            \
        lds16(aS + 12288 + t16, Ad + 12288 + t16);           \
    }
#define STAGE_B(buf, ksv)                                    \
    {                                                        \
        const signed char* bS = bT + ((size_t)(ksv) << 13);  \
        signed char* Bd = Bs[buf];                           \
        lds16(bS + t16,         Bd + t16);                   \
        lds16(bS + 4096 + t16,  Bd + 4096 + t16);            \
    }

    v16i acc[4][2] = {};

#define COMPUTE(AC, BC)                                                                              \
    {                                                                                                \
        const signed char* Ac = As[AC];                                                              \
        const signed char* Bc = Bs[BC];                                                              \
        _Pragma("unroll")                                                                            \
        for (int ks2 = 0; ks2 < 2; ks2++) {                                                          \
            v4i af[4], bf[2];                                                                        \
            _Pragma("unroll")                                                                        \
            for (int mt = 0; mt < 4; mt++)                                                           \
                af[mt] = *(const v4i*)(Ac + (((ks2 * 2 + lh) * 256 + wr * 128 + mt * 32 + l31) << 4)); \
            _Pragma("unroll")                                                                        \
            for (int nt = 0; nt < 2; nt++)                                                           \
                bf[nt] = *(const v4i*)(Bc + (((ks2 * 2 + lh) * 128 + wc * 64 + nt * 32 + l31) << 4)); \
            _Pragma("unroll")                                                                        \
            for (int mt = 0; mt < 4; mt++)                                                           \
                _Pragma("unroll")                                                                    \
                for (int nt = 0; nt < 2; nt++)                                                       \
                    acc[mt][nt] = __builtin_amdgcn_mfma_i32_32x32x32_i8(af[mt], bf[nt], acc[mt][nt], 0, 0, 0); \
        }                                                                                            \
    }

    // per-iter: stage B(ks+1), A(ks+2); wait vmcnt(10) = retire {B(ks), A(ks)};
    // raw barrier (no drain); compute; raw barrier (release bufs for overwrite).
#define ITER10(ksv, AC, BC, AS, BS)                          \
    {                                                        \
        STAGE_B(BS, (ksv) + 1);                              \
        STAGE_A(AS, (ksv) + 2);                              \
        asm volatile("s_waitcnt vmcnt(10)" ::: "memory");    \
        __builtin_amdgcn_s_barrier();                        \
        COMPUTE(AC, BC);                                     \
        __builtin_amdgcn_s_barrier();                        \
    }

    // prologue: queue = [B0(2), A0(4), A1(4)] = 10 outstanding
    STAGE_B(0, 0);
    STAGE_A(0, 0);
    STAGE_A(1, 1);

    // main loop: ks = 0..29, buffer indices AC=ks%3, BC=ks%2, AS=(ks+2)%3, BS=(ks+1)%2
    for (int ks = 0; ks < 30; ks += 6) {
        ITER10(ks + 0, 0, 0, 2, 1);
        ITER10(ks + 1, 1, 1, 0, 0);
        ITER10(ks + 2, 2, 0, 1, 1);
        ITER10(ks + 3, 0, 1, 2, 0);
        ITER10(ks + 4, 1, 0, 0, 1);
        ITER10(ks + 5, 2, 1, 1, 0);
    }

    // tail ks=30: stage B(31); wait vmcnt(6) = retire {A(30), B(30)}
    STAGE_B(1, 31);
    asm volatile("s_waitcnt vmcnt(6)" ::: "memory");
    __builtin_amdgcn_s_barrier();
    COMPUTE(0, 0);
    __builtin_amdgcn_s_barrier();
    // tail ks=31: wait vmcnt(0) = retire {A(31), B(31)}
    asm volatile("s_waitcnt vmcnt(0)" ::: "memory");
    __builtin_amdgcn_s_barrier();
    COMPUTE(1, 1);

#undef ITER10
#undef COMPUTE
#undef STAGE_A
#undef STAGE_B

    // epilogue: C/D 32x32 layout col=lane&31, row=(r&3)+8*(r>>2)+4*(lane>>5)
    float invsw = *invsw_p;
#pragma unroll
    for (int mt = 0; mt < 4; mt++) {
        int rowb = bm * 256 + wr * 128 + mt * 32 + (lh << 2);
        float sc[16];
#pragma unroll
        for (int r = 0; r < 16; r++)
            sc[r] = invsw / si[rowb + (r & 3) + ((r >> 2) << 3)];
#pragma unroll
        for (int nt = 0; nt < 2; nt++) {
            int col = bn * 128 + wc * 64 + nt * 32 + l31;
#pragma unroll
            for (int r = 0; r < 16; r++) {
                int row = rowb + (r & 3) + ((r >> 2) << 3);
                float vv = (float)acc[mt][nt][r] * sc[r];
                out[(size_t)row * N_DIM + col] = (float)(_Float16)vv;
            }
        }
    }
}

extern "C" void kernel_launch(void* const* d_in, const int* in_sizes, int n_in,
                              void* d_out, int out_size, void* d_ws, size_t ws_size,
                              hipStream_t stream) {
    const float* x = (const float*)d_in[0];
    const float* w = (const float*)d_in[1];
    float* out = (float*)d_out;
    char* ws = (char*)d_ws;

    double* part = (double*)ws;
    float* invsw = (float*)(ws + 2048);
    float* si = (float*)(ws + 4096);
    signed char* qw_t = (signed char*)(ws + 4096 + 65536);
    signed char* qx_t = qw_t + (size_t)N_DIM * K_DIM;

    k_wsum<<<256, 256, 0, stream>>>(w, part);
    k_quant_x<<<4096, 256, 0, stream>>>(x, qx_t, si);
    k_quant_w<<<512, 256, 0, stream>>>(w, qw_t, part, invsw);
    k_gemm<<<1024, 256, 0, stream>>>(qx_t, qw_t, si, invsw, out);
}

// Round 3
// 312.674 us; speedup vs baseline: 1.1075x; 1.0336x over previous
//
#include <hip/hip_runtime.h>

#define K_DIM 2048
#define N_DIM 2048
#define M_DIM 16384

typedef int v4i __attribute__((ext_vector_type(4)));
typedef int v16i __attribute__((ext_vector_type(16)));

// ---------------- ws layout ----------------
// [0]      double part[1024]     (8 KB)
// [8192]   float  invsw
// [12288]  float  si[16384]      (64 KB)
// [77824]  int8   qw_t           (4 MiB)  tiled [bn(16)][ks(32)][k16(4)][row(128)][16B]
// [+4MiB]  int8   qx_t           (32 MiB) tiled [bm(64)][ks(32)][k16(4)][row(256)][16B]

__device__ __forceinline__ void lds16(const void* g, void* l) {
    __builtin_amdgcn_global_load_lds(
        (const __attribute__((address_space(1))) unsigned int*)g,
        (__attribute__((address_space(3))) unsigned int*)l,
        16, 0, 0);
}

// ---------- kernel 1: per-block |W| partial sums (1024 blocks: 4x parallelism vs r1) ----------
__global__ __launch_bounds__(256) void k_wsum(const float* __restrict__ w,
                                              double* __restrict__ part) {
    int tid = blockIdx.x * 256 + threadIdx.x;
    const float4* w4 = (const float4*)w;
    double s = 0.0;
    for (int i = tid; i < (N_DIM * K_DIM / 4); i += 262144) {
        float4 v = w4[i];
        s += (double)fabsf(v.x);
        s += (double)fabsf(v.y);
        s += (double)fabsf(v.z);
        s += (double)fabsf(v.w);
    }
#pragma unroll
    for (int off = 32; off; off >>= 1) s += __shfl_xor(s, off, 64);
    __shared__ double sp[4];
    int lane = threadIdx.x & 63, wv = threadIdx.x >> 6;
    if (lane == 0) sp[wv] = s;
    __syncthreads();
    if (threadIdx.x == 0) part[blockIdx.x] = sp[0] + sp[1] + sp[2] + sp[3];
}

// ---------- kernel 2: reduce partials + ternary-quantize W (LDS-transposed 64B stores) ----------
__global__ __launch_bounds__(256) void k_quant_w(const float* __restrict__ w,
                                                 signed char* __restrict__ qw_t,
                                                 const double* __restrict__ part,
                                                 float* __restrict__ invsw_out) {
    // deterministic re-reduction of the 1024 partials (identical in every block)
    double s = part[threadIdx.x] + part[threadIdx.x + 256] +
               part[threadIdx.x + 512] + part[threadIdx.x + 768];
#pragma unroll
    for (int off = 32; off; off >>= 1) s += __shfl_xor(s, off, 64);
    __shared__ double sp[4];
    __shared__ float s_invsw;
    __shared__ int lbuf[2048];  // [chunk(128)=ks*4+k16][row4(4)][b(4)]
    int lane = threadIdx.x & 63, wv = threadIdx.x >> 6;
    if (lane == 0) sp[wv] = s;
    __syncthreads();
    if (threadIdx.x == 0) {
        double total = sp[0] + sp[1] + sp[2] + sp[3];
        float mean = (float)(total * (1.0 / (double)(N_DIM * K_DIM)));
        s_invsw = fmaxf(mean, 1e-5f);
        if (blockIdx.x == 0) *invsw_out = s_invsw;
    }
    __syncthreads();
    float sw = 1.0f / s_invsw;  // reference's sw

    int row = blockIdx.x * 4 + wv;           // 0..2047
    const float4* wr_ = (const float4*)(w + (size_t)row * K_DIM);
    int k16 = (lane >> 2) & 3, b = lane & 3, ksBase = lane >> 4;
#pragma unroll
    for (int c = 0; c < 8; c++) {
        float4 v = wr_[c * 64 + lane];
        int q0 = (int)fminf(fmaxf(rintf(v.x * sw), -1.f), 1.f);
        int q1 = (int)fminf(fmaxf(rintf(v.y * sw), -1.f), 1.f);
        int q2 = (int)fminf(fmaxf(rintf(v.z * sw), -1.f), 1.f);
        int q3 = (int)fminf(fmaxf(rintf(v.w * sw), -1.f), 1.f);
        int q = (q0 & 255) | ((q1 & 255) << 8) | ((q2 & 255) << 16) | ((q3 & 255) << 24);
        int ks = 4 * c + ksBase;
        lbuf[(ks * 4 + k16) * 16 + wv * 4 + b] = q;
    }
    __syncthreads();
    // coalesced stores: 16 threads emit one 64B chunk (4 rows x 16B)
    int bn = (blockIdx.x * 4) >> 7, ri0 = (blockIdx.x * 4) & 127;
    int* qdst = (int*)(qw_t + (size_t)bn * 262144 + (size_t)ri0 * 16);
#pragma unroll
    for (int r = 0; r < 8; r++) {
        int chunk = r * 16 + (threadIdx.x >> 4);       // ks*4+k16
        int i16 = threadIdx.x & 15;                    // row4*4+b
        int ks = chunk >> 2, kk = chunk & 3;
        int row4 = i16 >> 2, bb = i16 & 3;
        qdst[ks * 2048 + kk * 512 + row4 * 4 + bb] = lbuf[chunk * 16 + i16];
    }
}

// ---------- kernel 3: per-row int8-quantize X (LDS-transposed 64B stores) ----------
__global__ __launch_bounds__(256) void k_quant_x(const float* __restrict__ x,
                                                 signed char* __restrict__ qx_t,
                                                 float* __restrict__ si_out) {
    __shared__ int lbuf[2048];  // [chunk(128)=ks*4+k16][row4(4)][b(4)]
    int wv = threadIdx.x >> 6, lane = threadIdx.x & 63;
    int row = blockIdx.x * 4 + wv;
    const float4* xr = (const float4*)(x + (size_t)row * K_DIM);
    float4 v[8];
    float mx = 0.f;
#pragma unroll
    for (int c = 0; c < 8; c++) {
        v[c] = xr[c * 64 + lane];
        mx = fmaxf(mx, fmaxf(fmaxf(fabsf(v[c].x), fabsf(v[c].y)),
                             fmaxf(fabsf(v[c].z), fabsf(v[c].w))));
    }
#pragma unroll
    for (int off = 32; off; off >>= 1) mx = fmaxf(mx, __shfl_xor(mx, off, 64));
    float si = 127.0f / fmaxf(mx, 1e-5f);  // bit-exact vs reference
    if (lane == 0) si_out[row] = si;

    int k16 = (lane >> 2) & 3, b = lane & 3, ksBase = lane >> 4;
#pragma unroll
    for (int c = 0; c < 8; c++) {
        int q0 = (int)fminf(fmaxf(rintf(v[c].x * si), -128.f), 127.f);
        int q1 = (int)fminf(fmaxf(rintf(v[c].y * si), -128.f), 127.f);
        int q2 = (int)fminf(fmaxf(rintf(v[c].z * si), -128.f), 127.f);
        int q3 = (int)fminf(fmaxf(rintf(v[c].w * si), -128.f), 127.f);
        int q = (q0 & 255) | ((q1 & 255) << 8) | ((q2 & 255) << 16) | ((q3 & 255) << 24);
        int ks = 4 * c + ksBase;
        lbuf[(ks * 4 + k16) * 16 + wv * 4 + b] = q;
    }
    __syncthreads();
    int bm = (blockIdx.x * 4) >> 8, ri0 = (blockIdx.x * 4) & 255;
    int* qdst = (int*)(qx_t + (size_t)bm * 524288 + (size_t)ri0 * 16);
#pragma unroll
    for (int r = 0; r < 8; r++) {
        int chunk = r * 16 + (threadIdx.x >> 4);
        int i16 = threadIdx.x & 15;
        int ks = chunk >> 2, kk = chunk & 3;
        int row4 = i16 >> 2, bb = i16 & 3;
        qdst[ks * 4096 + kk * 1024 + row4 * 4 + bb] = lbuf[chunk * 16 + i16];
    }
}

// ---------- kernel 4: int8 GEMM, 256x128 block, 32x32x32 MFMA ----------
// ROUND 2 CHANGE (phase interleave + single barrier + T5):
//   * wait moved to iteration TOP: vmcnt(4) retires exactly {B(ks),A(ks)}.
//     With stage issued AFTER the barrier, the trailing barrier is provably
//     removable (writer passed barrier => all waves' lgkm-awaited ds_reads
//     of the target buffer already retired) -> ONE barrier per K-step.
//   * compute split into two k-half phases; STAGE_B between phase1 reads and
//     MFMA, STAGE_A in phase2 -> loads/ds_reads/MFMA interleave.
//   * s_setprio(1) around each 8-MFMA cluster (T5: phase-split gives the
//     scheduler wave-role diversity to arbitrate).
__global__ __launch_bounds__(256, 2) void k_gemm(const signed char* __restrict__ qx_t,
                                                 const signed char* __restrict__ qw_t,
                                                 const float* __restrict__ si,
                                                 const float* __restrict__ invsw_p,
                                                 float* __restrict__ out) {
    __shared__ __align__(16) signed char As[3][16384];  // [k16(4)][row(256)][16B]
    __shared__ __align__(16) signed char Bs[2][8192];   // [k16(4)][row(128)][16B]
    const int t = threadIdx.x;
    const int lane = t & 63, wv = t >> 6;
    const int wr = wv >> 1, wc = wv & 1;   // 2x2 wave grid; wave tile 128x64
    const int l31 = lane & 31, lh = lane >> 5;

    // T1: bijective chunked XCD swizzle (nwg=1024, 8 XCDs, 128 blocks/XCD)
    const int wg = blockIdx.x;
    const int swz = (wg & 7) * 128 + (wg >> 3);
    const int bn = swz & 15, bm = swz >> 4;

    const signed char* aT = qx_t + (size_t)bm * 524288;
    const signed char* bT = qw_t + (size_t)bn * 262144;
    const int t16 = t << 4;

#define STAGE_A(buf, ksv)                                    \
    {                                                        \
        const signed char* aS = aT + ((size_t)(ksv) << 14);  \
        signed char* Ad = As[buf];                           \
        lds16(aS + t16,         Ad + t16);                   \
        lds16(aS + 4096 + t16,  Ad + 4096 + t16);            \
        lds16(aS + 8192 + t16,  Ad + 8192 + t16);            \
        lds16(aS + 12288 + t16, Ad + 12288 + t16);           \
    }
#define STAGE_B(buf, ksv)                                    \
    {                                                        \
        const signed char* bS = bT + ((size_t)(ksv) << 13);  \
        signed char* Bd = Bs[buf];                           \
        lds16(bS + t16,         Bd + t16);                   \
        lds16(bS + 4096 + t16,  Bd + 4096 + t16);            \
    }

    v16i acc[4][2] = {};

#define READ_HALF(AC, BC, h, af, bf)                                                                 \
    _Pragma("unroll") for (int mt = 0; mt < 4; mt++)                                                 \
        af[mt] = *(const v4i*)(As[AC] + ((((h) * 2 + lh) * 256 + wr * 128 + mt * 32 + l31) << 4));   \
    _Pragma("unroll") for (int nt = 0; nt < 2; nt++)                                                 \
        bf[nt] = *(const v4i*)(Bs[BC] + ((((h) * 2 + lh) * 128 + wc * 64 + nt * 32 + l31) << 4));

#define MFMA8(af, bf)                                                                                \
    __builtin_amdgcn_s_setprio(1);                                                                   \
    _Pragma("unroll") for (int mt = 0; mt < 4; mt++)                                                 \
        _Pragma("unroll") for (int nt = 0; nt < 2; nt++)                                             \
            acc[mt][nt] = __builtin_amdgcn_mfma_i32_32x32x32_i8(af[mt], bf[nt], acc[mt][nt], 0, 0, 0); \
    __builtin_amdgcn_s_setprio(0);

    // per-iter: wait vmcnt(4) (retire {B(ks),A(ks)}); single barrier; then
    // {phase1 reads, STAGE_B(ks+1), MFMA} {phase2 reads, STAGE_A(ks+2), MFMA}.
#define ITER(ksv, AC, BC, AS, BS)                            \
    {                                                        \
        asm volatile("s_waitcnt vmcnt(4)" ::: "memory");     \
        __builtin_amdgcn_s_barrier();                        \
        __builtin_amdgcn_sched_barrier(0);                   \
        v4i af[4], bf[2];                                    \
        READ_HALF(AC, BC, 0, af, bf);                        \
        STAGE_B(BS, (ksv) + 1);                              \
        MFMA8(af, bf);                                       \
        READ_HALF(AC, BC, 1, af, bf);                        \
        STAGE_A(AS, (ksv) + 2);                              \
        MFMA8(af, bf);                                       \
    }

    // prologue: FIFO = [B0(2), A0(4), A1(4)] = 10 outstanding
    STAGE_B(0, 0);
    STAGE_A(0, 0);
    STAGE_A(1, 1);

    // main loop: ks = 0..29; AC=ks%3, BC=ks%2, AS=(ks+2)%3, BS=(ks+1)%2
    for (int ks = 0; ks < 30; ks += 6) {
        ITER(ks + 0, 0, 0, 2, 1);
        ITER(ks + 1, 1, 1, 0, 0);
        ITER(ks + 2, 2, 0, 1, 1);
        ITER(ks + 3, 0, 1, 2, 0);
        ITER(ks + 4, 1, 0, 0, 1);
        ITER(ks + 5, 2, 1, 1, 0);
    }

    // tail ks=30: outstanding [A30(4),B30(2),A31(4)] -> vmcnt(4) retires A30,B30
    {
        asm volatile("s_waitcnt vmcnt(4)" ::: "memory");
        __builtin_amdgcn_s_barrier();
        __builtin_amdgcn_sched_barrier(0);
        v4i af[4], bf[2];
        READ_HALF(0, 0, 0, af, bf);
        STAGE_B(1, 31);
        MFMA8(af, bf);
        READ_HALF(0, 0, 1, af, bf);
        MFMA8(af, bf);
    }
    // tail ks=31: outstanding [A31(4),B31(2)] -> drain
    {
        asm volatile("s_waitcnt vmcnt(0)" ::: "memory");
        __builtin_amdgcn_s_barrier();
        __builtin_amdgcn_sched_barrier(0);
        v4i af[4], bf[2];
        READ_HALF(1, 1, 0, af, bf);
        MFMA8(af, bf);
        READ_HALF(1, 1, 1, af, bf);
        MFMA8(af, bf);
    }

#undef ITER
#undef MFMA8
#undef READ_HALF
#undef STAGE_A
#undef STAGE_B

    // epilogue: C/D 32x32 layout col=lane&31, row=(r&3)+8*(r>>2)+4*(lane>>5)
    float invsw = *invsw_p;
#pragma unroll
    for (int mt = 0; mt < 4; mt++) {
        int rowb = bm * 256 + wr * 128 + mt * 32 + (lh << 2);
        float sc[16];
#pragma unroll
        for (int r = 0; r < 16; r++)
            sc[r] = invsw / si[rowb + (r & 3) + ((r >> 2) << 3)];
#pragma unroll
        for (int nt = 0; nt < 2; nt++) {
            int col = bn * 128 + wc * 64 + nt * 32 + l31;
#pragma unroll
            for (int r = 0; r < 16; r++) {
                int row = rowb + (r & 3) + ((r >> 2) << 3);
                float vv = (float)acc[mt][nt][r] * sc[r];
                out[(size_t)row * N_DIM + col] = (float)(_Float16)vv;
            }
        }
    }
}

extern "C" void kernel_launch(void* const* d_in, const int* in_sizes, int n_in,
                              void* d_out, int out_size, void* d_ws, size_t ws_size,
                              hipStream_t stream) {
    const float* x = (const float*)d_in[0];
    const float* w = (const float*)d_in[1];
    float* out = (float*)d_out;
    char* ws = (char*)d_ws;

    double* part = (double*)ws;
    float* invsw = (float*)(ws + 8192);
    float* si = (float*)(ws + 12288);
    signed char* qw_t = (signed char*)(ws + 12288 + 65536);
    signed char* qx_t = qw_t + (size_t)N_DIM * K_DIM;

    k_wsum<<<1024, 256, 0, stream>>>(w, part);
    k_quant_x<<<4096, 256, 0, stream>>>(x, qx_t, si);
    k_quant_w<<<512, 256, 0, stream>>>(w, qw_t, part, invsw);
    k_gemm<<<1024, 256, 0, stream>>>(qx_t, qw_t, si, invsw, out);
}